// Round 2
// baseline (2337.620 us; speedup 1.0000x reference)
//
#include <hip/hip_runtime.h>
#include <stdint.h>
#include <math.h>

// RNN predictor: B=2048, T=1024 teacher-forced + FUT=64 autoregressive steps,
// H=128. f32 (no fp32 MFMA on CDNA4 -> vector ALU).
//
// Round-2 design: weights fully register-resident, one wave per sample.
//  - lane l owns output units j0=2l, j1=2l+1; weights W_hh[j0/j1][k] held as
//    64 float2 k-pairs each => 256 VGPRs of weights. 1 wave/SIMD by design.
//  - hidden state lives in registers: lane l holds h[2l] (hA), h[2l+1] (hB).
//  - broadcast h[k] via v_readlane -> SGPR pair, consumed as the scalar
//    operand of v_pk_fma_f32 (packed f32 FMA: 2 MACs/lane/instr).
//  - accA = (even-k partial, odd-k partial) for j0; horizontal add at end.
//  - no LDS, no barriers, no cross-wave traffic in the 1088-step loop.

#define TLEN  1024
#define FUT   64
#define HID   128

typedef float f2 __attribute__((ext_vector_type(2)));

__device__ __forceinline__ float fast_tanh(float v) {
    // 1 - 2/(exp(2v)+1); saturates correctly for large |v|.
    return 1.0f - 2.0f / (__expf(2.0f * v) + 1.0f);
}

__global__ __launch_bounds__(256, 1) void rnn_kernel(
    const float* __restrict__ x,      // [B, T]
    const float* __restrict__ W_ih,   // [H, 1]
    const float* __restrict__ W_hh,   // [H, H]
    const float* __restrict__ b_ih,   // [H]
    const float* __restrict__ b_hh,   // [H]
    const float* __restrict__ W_out,  // [1, H]
    const float* __restrict__ b_out,  // [1]
    float* __restrict__ out)          // [B, T+FUT]
{
    const int lane = threadIdx.x & 63;
    const int wid  = threadIdx.x >> 6;
    const int s    = blockIdx.x * 4 + wid;   // one sample per wave
    const int j0   = lane * 2;

    // Register-resident weights: wA[p] = (W[j0][2p], W[j0][2p+1]).
    f2 wA[64], wB[64];
    #pragma unroll
    for (int p = 0; p < 64; ++p) {
        wA[p] = *(const f2*)&W_hh[(size_t)j0 * HID + 2 * p];
        wB[p] = *(const f2*)&W_hh[(size_t)(j0 + 1) * HID + 2 * p];
    }

    const f2    wih  = { W_ih[j0], W_ih[j0 + 1] };
    const float b0   = b_ih[j0]     + b_hh[j0];
    const float b1   = b_ih[j0 + 1] + b_hh[j0 + 1];
    const f2    wout = { W_out[j0], W_out[j0 + 1] };
    const float bo   = b_out[0];

    const float* xrow = x   + (size_t)s * TLEN;
    float*       orow = out + (size_t)s * (TLEN + FUT);

    int   hAi = 0, hBi = 0;          // bit patterns of h[2l], h[2l+1] (0.0f)
    float o_prev = 0.0f;
    float xcur = xrow[0];

    for (int i = 0; i < TLEN + FUT; ++i) {
        const float inp = (i < TLEN) ? xcur : o_prev;
        if (i + 1 < TLEN) xcur = xrow[i + 1];   // uniform-branch prefetch

        f2 accA; accA.x = b0; accA.y = 0.0f;    // (even-k, odd-k) partials, j0
        f2 accB; accB.x = b1; accB.y = 0.0f;    // j1

        #pragma unroll
        for (int p = 0; p < 64; ++p) {
            const uint32_t rlo = (uint32_t)__builtin_amdgcn_readlane(hAi, p); // h[2p]
            const uint32_t rhi = (uint32_t)__builtin_amdgcn_readlane(hBi, p); // h[2p+1]
            const uint64_t h2 = ((uint64_t)rhi << 32) | rlo;  // SGPR pair (SALU pack)
            asm("v_pk_fma_f32 %0, %2, %1, %0" : "+v"(accA) : "v"(wA[p]), "s"(h2));
            asm("v_pk_fma_f32 %0, %2, %1, %0" : "+v"(accB) : "v"(wB[p]), "s"(h2));
        }

        const float S0 = fmaf(inp, wih.x, accA.x + accA.y);
        const float S1 = fmaf(inp, wih.y, accB.x + accB.y);
        const float hA = fast_tanh(S0);
        const float hB = fast_tanh(S1);
        hAi = __builtin_bit_cast(int, hA);
        hBi = __builtin_bit_cast(int, hB);

        // out = W_out . h_new + b_out  -- butterfly over all 64 lanes; result
        // identical in every lane (same tree shape, add is commutative).
        float po = hA * wout.x + hB * wout.y;
        po += __shfl_xor(po, 1);
        po += __shfl_xor(po, 2);
        po += __shfl_xor(po, 4);
        po += __shfl_xor(po, 8);
        po += __shfl_xor(po, 16);
        po += __shfl_xor(po, 32);
        const float o = po + bo;

        if (lane == 0) orow[i] = o;
        o_prev = o;   // autoregressive input for i >= TLEN
    }
}

extern "C" void kernel_launch(void* const* d_in, const int* in_sizes, int n_in,
                              void* d_out, int out_size, void* d_ws, size_t ws_size,
                              hipStream_t stream) {
    const float* x     = (const float*)d_in[0];
    const float* W_ih  = (const float*)d_in[1];
    const float* W_hh  = (const float*)d_in[2];
    const float* b_ih  = (const float*)d_in[3];
    const float* b_hh  = (const float*)d_in[4];
    const float* W_out = (const float*)d_in[5];
    const float* b_out = (const float*)d_in[6];
    float* out = (float*)d_out;

    dim3 grid(2048 / 4);   // 512 blocks x 4 waves = 2048 waves = 1 per sample
    dim3 block(256);
    rnn_kernel<<<grid, block, 0, stream>>>(x, W_ih, W_hh, b_ih, b_hh,
                                           W_out, b_out, out);
}

// Round 3
// 1258.819 us; speedup vs baseline: 1.8570x; 1.8570x over previous
//
#include <hip/hip_runtime.h>
#include <stdint.h>
#include <math.h>

// RNN predictor: B=2048, T=1024 teacher-forced + FUT=64 autoregressive, H=128.
// Round-3: MFMA path. Per block: 16 samples, 4 waves; per step
//   S[16,128] = h[16,128] @ W_hh^T + bias + inp*W_ih;  h' = tanh(S)
// via mfma_f32_16x16x32_bf16 with split-bf16 (hi+lo) operands:
//   W*h ~= Whi*hhi + Whi*hlo + Wlo*hhi   (lo*lo dropped, ~2^-16 rel)
// Weight B-fragments live permanently in VGPRs (64 VGPR/wave). h is
// exchanged between waves via XOR-swizzled bf16 LDS (double-buffered),
// ONE barrier per step. Output projection o = h.W_out + b_out computed from
// per-lane f32 C-frags (full precision), reduced via shfl + tiny LDS buffer
// (double-buffered), software-rotated into the next iteration.

#define TLEN  1024
#define FUT   64
#define HID   128
#define SPB   16
#define NT    256
#define NSTEP (TLEN + FUT)
#define XCH   128

typedef float f32x4 __attribute__((ext_vector_type(4)));
typedef short bf16x8 __attribute__((ext_vector_type(8)));

__device__ __forceinline__ float fast_tanh(float v) {
    return 1.0f - 2.0f / (__expf(2.0f * v) + 1.0f);   // saturates correctly
}
__device__ __forceinline__ unsigned short bf16_rn(float f) {
    uint32_t u = __builtin_bit_cast(uint32_t, f);
    uint32_t r = (u + 0x7fffu + ((u >> 16) & 1u)) >> 16;  // RNE
    return (unsigned short)r;
}
__device__ __forceinline__ float bf16f(unsigned short h) {
    uint32_t u = (uint32_t)h << 16;
    return __builtin_bit_cast(float, u);
}

__global__ __launch_bounds__(NT, 1) void rnn_kernel(
    const float* __restrict__ x,      // [B, T]
    const float* __restrict__ W_ih,   // [H, 1]
    const float* __restrict__ W_hh,   // [H, H]
    const float* __restrict__ b_ih,   // [H]
    const float* __restrict__ b_hh,   // [H]
    const float* __restrict__ W_out,  // [1, H]
    const float* __restrict__ b_out,  // [1]
    float* __restrict__ out)          // [B, T+FUT]
{
    __shared__ __align__(16) unsigned short hhi[2][SPB * HID];  // bf16 hi, 2x4KB
    __shared__ __align__(16) unsigned short hlo[2][SPB * HID];  // bf16 lo
    __shared__ __align__(16) float xstg[XCH][SPB];              // staged x chunk
    __shared__ __align__(16) float opart[2][SPB][4];            // o partials [m][wave]

    const int tid  = threadIdx.x;
    const int lane = tid & 63;
    const int wid  = tid >> 6;        // wave 0..3: owns N-cols 32w..32w+31
    const int l15  = lane & 15;
    const int g    = lane >> 4;       // lane quarter
    const int s0   = blockIdx.x * SPB;

    // ---- persistent weight B-fragments (bf16 hi/lo), 64 VGPRs ----
    // B layout for 16x16x32: n = lane&15, k = 8*(lane>>4)+e (+32*kc).
    // B[k][n] = (W_hh^T)[k][n] = W_hh[n][k]  -> read row j, contiguous k.
    const int j0 = wid * 32 + l15;    // tile-0 column (hidden unit index)
    const int j1 = j0 + 16;           // tile-1 column
    bf16x8 whi0[4], wlo0[4], whi1[4], wlo1[4];
    {
        const float* r0 = W_hh + (size_t)j0 * HID;
        const float* r1 = W_hh + (size_t)j1 * HID;
        #pragma unroll
        for (int kc = 0; kc < 4; ++kc) {
            const int koff = kc * 32 + g * 8;
            #pragma unroll
            for (int e = 0; e < 8; ++e) {
                float w = r0[koff + e];
                unsigned short h = bf16_rn(w);
                whi0[kc][e] = (short)h;
                wlo0[kc][e] = (short)bf16_rn(w - bf16f(h));
                w = r1[koff + e];
                h = bf16_rn(w);
                whi1[kc][e] = (short)h;
                wlo1[kc][e] = (short)bf16_rn(w - bf16f(h));
            }
        }
    }
    const float bias0 = b_ih[j0] + b_hh[j0];
    const float bias1 = b_ih[j1] + b_hh[j1];
    const float wih0  = W_ih[j0], wih1 = W_ih[j1];
    const float wout0 = W_out[j0], wout1 = W_out[j1];
    const float bo    = b_out[0];

    // ---- precomputed LDS byte offsets (XOR-swizzled: byte ^= (row&7)<<4) ----
    // A-frag read: row s = l15, 16B at k = 8*g + 32*kc.
    int aoff[4];
    #pragma unroll
    for (int kc = 0; kc < 4; ++kc)
        aoff[kc] = l15 * 256 + ((g * 16 + kc * 64) ^ ((l15 & 7) << 4));
    // h-write: C-frag reg r -> row m = 4g+r, col j (tile0/tile1), 2B each.
    int woffA[4], woffB[4];
    #pragma unroll
    for (int r = 0; r < 4; ++r) {
        const int row = g * 4 + r;
        const int swz = (row & 7) << 4;
        woffA[r] = row * 256 + ((j0 * 2) ^ swz);
        woffB[r] = row * 256 + ((j1 * 2) ^ swz);
    }

    // zero h0
    for (int idx = tid; idx < SPB * HID; idx += NT) {
        hhi[0][idx] = 0; hlo[0][idx] = 0;
    }
    __syncthreads();

    float fin0 = 0.f, fin1 = 0.f, fin2 = 0.f, fin3 = 0.f;  // AR inputs

    for (int i = 0; i < NSTEP; ++i) {
        const int p = i & 1;

        // refill x chunk (transposed) every 128 teacher steps
        if (i < TLEN && (i & (XCH - 1)) == 0) {
            for (int idx = tid; idx < XCH * SPB; idx += NT) {
                const int t = idx >> 4, s = idx & 15;
                xstg[t][s] = x[(size_t)(s0 + s) * TLEN + (i + t)];
            }
            __syncthreads();
        }

        // A-fragments of h (written last step, fenced by end-of-step barrier)
        const char* hb = (const char*)hhi[p];
        const char* lb = (const char*)hlo[p];
        bf16x8 ahi[4], alo[4];
        #pragma unroll
        for (int kc = 0; kc < 4; ++kc) {
            ahi[kc] = *(const bf16x8*)(hb + aoff[kc]);
            alo[kc] = *(const bf16x8*)(lb + aoff[kc]);
        }

        // rotated tail of step i-1: finish o, store it, update AR inputs.
        if (i > 0) {
            const int qm = (i - 1) & 1;
            const f32x4 ov = *(const f32x4*)&opart[qm][l15][0];
            const float o = ov[0] + ov[1] + ov[2] + ov[3] + bo;
            if (tid < 16) out[(size_t)(s0 + tid) * NSTEP + (i - 1)] = o;
            fin0 = __shfl(o, g * 4 + 0);
            fin1 = __shfl(o, g * 4 + 1);
            fin2 = __shfl(o, g * 4 + 2);
            fin3 = __shfl(o, g * 4 + 3);
        }

        // 24 MFMA: Whi*hhi + Whi*hlo + Wlo*hhi for both N-tiles
        f32x4 acc0 = {0.f, 0.f, 0.f, 0.f};
        f32x4 acc1 = {0.f, 0.f, 0.f, 0.f};
        #pragma unroll
        for (int kc = 0; kc < 4; ++kc) {
            acc0 = __builtin_amdgcn_mfma_f32_16x16x32_bf16(ahi[kc], whi0[kc], acc0, 0, 0, 0);
            acc1 = __builtin_amdgcn_mfma_f32_16x16x32_bf16(ahi[kc], whi1[kc], acc1, 0, 0, 0);
            acc0 = __builtin_amdgcn_mfma_f32_16x16x32_bf16(alo[kc], whi0[kc], acc0, 0, 0, 0);
            acc1 = __builtin_amdgcn_mfma_f32_16x16x32_bf16(alo[kc], whi1[kc], acc1, 0, 0, 0);
            acc0 = __builtin_amdgcn_mfma_f32_16x16x32_bf16(ahi[kc], wlo0[kc], acc0, 0, 0, 0);
            acc1 = __builtin_amdgcn_mfma_f32_16x16x32_bf16(ahi[kc], wlo1[kc], acc1, 0, 0, 0);
        }

        // per-row inputs for this step (uniform branch)
        float in0, in1, in2, in3;
        if (i < TLEN) {
            const f32x4 xv = *(const f32x4*)&xstg[i & (XCH - 1)][g * 4];
            in0 = xv[0]; in1 = xv[1]; in2 = xv[2]; in3 = xv[3];
        } else {
            in0 = fin0; in1 = fin1; in2 = fin2; in3 = fin3;
        }

        // epilogue: bias + input term, tanh, hi/lo split, write h', o-partials
        unsigned short* hwq = hhi[p ^ 1];
        unsigned short* lwq = hlo[p ^ 1];
        float op[4];
        #pragma unroll
        for (int r = 0; r < 4; ++r) {
            const float inr = (r == 0) ? in0 : (r == 1) ? in1 : (r == 2) ? in2 : in3;
            const float S0 = acc0[r] + bias0 + inr * wih0;
            const float S1 = acc1[r] + bias1 + inr * wih1;
            const float h0 = fast_tanh(S0);
            const float h1 = fast_tanh(S1);
            op[r] = h0 * wout0 + h1 * wout1;
            const unsigned short u0 = bf16_rn(h0);
            const unsigned short u1 = bf16_rn(h1);
            *(unsigned short*)((char*)hwq + woffA[r]) = u0;
            *(unsigned short*)((char*)hwq + woffB[r]) = u1;
            *(unsigned short*)((char*)lwq + woffA[r]) = bf16_rn(h0 - bf16f(u0));
            *(unsigned short*)((char*)lwq + woffB[r]) = bf16_rn(h1 - bf16f(u1));
        }
        // reduce o-partials over the 16 lanes of each quarter (j within tile)
        #pragma unroll
        for (int r = 0; r < 4; ++r) {
            op[r] += __shfl_xor(op[r], 1);
            op[r] += __shfl_xor(op[r], 2);
            op[r] += __shfl_xor(op[r], 4);
            op[r] += __shfl_xor(op[r], 8);
        }
        if (l15 == 0) {
            opart[p][g * 4 + 0][wid] = op[0];
            opart[p][g * 4 + 1][wid] = op[1];
            opart[p][g * 4 + 2][wid] = op[2];
            opart[p][g * 4 + 3][wid] = op[3];
        }
        __syncthreads();   // the ONE per-step barrier
    }

    // final tail: o for step NSTEP-1
    {
        const int qm = (NSTEP - 1) & 1;
        const f32x4 ov = *(const f32x4*)&opart[qm][l15][0];
        const float o = ov[0] + ov[1] + ov[2] + ov[3] + bo;
        if (tid < 16) out[(size_t)(s0 + tid) * NSTEP + (NSTEP - 1)] = o;
    }
}

extern "C" void kernel_launch(void* const* d_in, const int* in_sizes, int n_in,
                              void* d_out, int out_size, void* d_ws, size_t ws_size,
                              hipStream_t stream) {
    const float* x     = (const float*)d_in[0];
    const float* W_ih  = (const float*)d_in[1];
    const float* W_hh  = (const float*)d_in[2];
    const float* b_ih  = (const float*)d_in[3];
    const float* b_hh  = (const float*)d_in[4];
    const float* W_out = (const float*)d_in[5];
    const float* b_out = (const float*)d_in[6];
    float* out = (float*)d_out;

    dim3 grid(2048 / SPB);   // 128 blocks x 16 samples
    dim3 block(NT);
    rnn_kernel<<<grid, block, 0, stream>>>(x, W_ih, W_hh, b_ih, b_hh,
                                           W_out, b_out, out);
}

// Round 4
// 1203.678 us; speedup vs baseline: 1.9421x; 1.0458x over previous
//
#include <hip/hip_runtime.h>
#include <stdint.h>
#include <math.h>

// RNN predictor: B=2048, T=1024 teacher-forced + FUT=64 autoregressive, H=128.
// Round-4: round-3 MFMA structure (verified fragment maps / swizzle) with the
// per-step chain cut down:
//  - o buffered in LDS (double-buffered), flushed every 64 steps as float4 ->
//    no per-step global store, no vmcnt(0) drain at the step barrier.
//  - o-partials reduced via 2 shfl stages + 4 LDS b32 writes (rides the step
//    barrier); next step: one f32x4 read + 3 adds + 2 shfls. Replaces the
//    16-shfl (4 dependent bpermute stages) reduction.
//  - 6 independent MFMA accumulator chains (3 products x 2 tiles) -> dep
//    distance ~29 cyc > MFMA latency, no stalls.
//  - v_cvt_pk_bf16_f32 for the hi/lo split of h'.
//  - coalesced x staging; AR fin-broadcast shfls only when i >= TLEN.

#define TLEN  1024
#define FUT   64
#define HID   128
#define SPB   16
#define NT    256
#define NSTEP (TLEN + FUT)

typedef float f32x4 __attribute__((ext_vector_type(4)));
typedef short bf16x8 __attribute__((ext_vector_type(8)));

__device__ __forceinline__ float fast_tanh(float v) {
    return 1.0f - 2.0f / (__expf(2.0f * v) + 1.0f);   // saturates correctly
}
__device__ __forceinline__ unsigned short bf16_rn(float f) {
    uint32_t u = __builtin_bit_cast(uint32_t, f);
    uint32_t r = (u + 0x7fffu + ((u >> 16) & 1u)) >> 16;  // RNE
    return (unsigned short)r;
}
__device__ __forceinline__ float bf16f(unsigned short h) {
    uint32_t u = (uint32_t)h << 16;
    return __builtin_bit_cast(float, u);
}

__global__ __launch_bounds__(NT, 1) void rnn_kernel(
    const float* __restrict__ x,      // [B, T]
    const float* __restrict__ W_ih,   // [H, 1]
    const float* __restrict__ W_hh,   // [H, H]
    const float* __restrict__ b_ih,   // [H]
    const float* __restrict__ b_hh,   // [H]
    const float* __restrict__ W_out,  // [1, H]
    const float* __restrict__ b_out,  // [1]
    float* __restrict__ out)          // [B, T+FUT]
{
    __shared__ __align__(16) unsigned short hhi[2][SPB * HID];  // bf16 hi
    __shared__ __align__(16) unsigned short hlo[2][SPB * HID];  // bf16 lo
    __shared__ __align__(16) float xstg[128][20];               // x chunk, padded
    __shared__ __align__(16) float opart[2][SPB][20];           // o partials, padded
    __shared__ __align__(16) float outbuf[2][SPB][68];          // o ring, padded

    const int tid  = threadIdx.x;
    const int lane = tid & 63;
    const int wid  = tid >> 6;        // wave 0..3: owns N-cols 32w..32w+31
    const int l15  = lane & 15;
    const int g    = lane >> 4;       // lane quarter
    const int s0   = blockIdx.x * SPB;

    // ---- persistent weight B-fragments (bf16 hi/lo) ----
    // B layout for 16x16x32: n = lane&15, k = 8*(lane>>4)+e (+32*kc).
    const int j0 = wid * 32 + l15;
    const int j1 = j0 + 16;
    bf16x8 whi0[4], wlo0[4], whi1[4], wlo1[4];
    {
        const float* r0 = W_hh + (size_t)j0 * HID;
        const float* r1 = W_hh + (size_t)j1 * HID;
        #pragma unroll
        for (int kc = 0; kc < 4; ++kc) {
            const int koff = kc * 32 + g * 8;
            #pragma unroll
            for (int e = 0; e < 8; ++e) {
                float w = r0[koff + e];
                unsigned short h = bf16_rn(w);
                whi0[kc][e] = (short)h;
                wlo0[kc][e] = (short)bf16_rn(w - bf16f(h));
                w = r1[koff + e];
                h = bf16_rn(w);
                whi1[kc][e] = (short)h;
                wlo1[kc][e] = (short)bf16_rn(w - bf16f(h));
            }
        }
    }
    const float bias0 = b_ih[j0] + b_hh[j0];
    const float bias1 = b_ih[j1] + b_hh[j1];
    const float wih0  = W_ih[j0], wih1 = W_ih[j1];
    const float wout0 = W_out[j0], wout1 = W_out[j1];
    const float bo    = b_out[0];

    // ---- LDS byte offsets (XOR swizzle: byte ^= (row&7)<<4), as round 3 ----
    int aoff[4];
    #pragma unroll
    for (int kc = 0; kc < 4; ++kc)
        aoff[kc] = l15 * 256 + ((g * 16 + kc * 64) ^ ((l15 & 7) << 4));
    int woffA[4], woffB[4];
    #pragma unroll
    for (int r = 0; r < 4; ++r) {
        const int row = g * 4 + r;
        const int swz = (row & 7) << 4;
        woffA[r] = row * 256 + ((j0 * 2) ^ swz);
        woffB[r] = row * 256 + ((j1 * 2) ^ swz);
    }

    for (int idx = tid; idx < SPB * HID; idx += NT) {
        hhi[0][idx] = 0; hlo[0][idx] = 0;
    }
    __syncthreads();

    for (int i = 0; i < NSTEP; ++i) {
        const int p = i & 1;

        // refill x chunk every 128 teacher steps (coalesced along t)
        if (i < TLEN && (i & 127) == 0) {
            #pragma unroll
            for (int pass = 0; pass < 8; ++pass) {
                const int idx = pass * NT + tid;
                const int t = idx & 127, s = idx >> 7;
                xstg[t][s] = x[(size_t)(s0 + s) * TLEN + (i + t)];
            }
            __syncthreads();
        }

        // flush a full 64-step output buffer (o_{i-65} .. o_{i-2})
        if (i > 64 && (i & 63) == 1) {
            const int q = ((i - 65) >> 6) & 1;
            const int base = i - 65;
            const int s = tid >> 4, c4 = (tid & 15) * 4;
            const f32x4 v = *(const f32x4*)&outbuf[q][s][c4];
            *(f32x4*)&out[(size_t)(s0 + s) * NSTEP + base + c4] = v;
        }

        // A-fragments of h + o-partials of step i-1
        const char* hb = (const char*)hhi[p];
        const char* lb = (const char*)hlo[p];
        bf16x8 ahi[4], alo[4];
        #pragma unroll
        for (int kc = 0; kc < 4; ++kc) {
            ahi[kc] = *(const bf16x8*)(hb + aoff[kc]);
            alo[kc] = *(const bf16x8*)(lb + aoff[kc]);
        }
        const f32x4 opv = *(const f32x4*)&opart[p ^ 1][l15][4 * g];  // garbage at i==0 (unused)

        // 24 MFMA in 6 independent chains
        f32x4 aA0 = {0.f,0.f,0.f,0.f}, aB0 = aA0, aC0 = aA0;
        f32x4 aA1 = aA0, aB1 = aA0, aC1 = aA0;
        #pragma unroll
        for (int kc = 0; kc < 4; ++kc) {
            aA0 = __builtin_amdgcn_mfma_f32_16x16x32_bf16(ahi[kc], whi0[kc], aA0, 0, 0, 0);
            aA1 = __builtin_amdgcn_mfma_f32_16x16x32_bf16(ahi[kc], whi1[kc], aA1, 0, 0, 0);
            aB0 = __builtin_amdgcn_mfma_f32_16x16x32_bf16(alo[kc], whi0[kc], aB0, 0, 0, 0);
            aB1 = __builtin_amdgcn_mfma_f32_16x16x32_bf16(alo[kc], whi1[kc], aB1, 0, 0, 0);
            aC0 = __builtin_amdgcn_mfma_f32_16x16x32_bf16(ahi[kc], wlo0[kc], aC0, 0, 0, 0);
            aC1 = __builtin_amdgcn_mfma_f32_16x16x32_bf16(ahi[kc], wlo1[kc], aC1, 0, 0, 0);
        }

        // finish o_{i-1}: sum 4 local partials + cross-quarter butterfly
        float o = 0.f;
        if (i > 0) {
            float osum = opv[0] + opv[1] + opv[2] + opv[3];
            osum += __shfl_xor(osum, 16);
            osum += __shfl_xor(osum, 32);
            o = osum + bo;
            if (tid < 16) outbuf[((i - 1) >> 6) & 1][l15][(i - 1) & 63] = o;
        }

        // per-row inputs (uniform branch)
        float in0, in1, in2, in3;
        if (i < TLEN) {
            const f32x4 xv = *(const f32x4*)&xstg[i & 127][4 * g];
            in0 = xv[0]; in1 = xv[1]; in2 = xv[2]; in3 = xv[3];
        } else {
            in0 = __shfl(o, 4 * g + 0);
            in1 = __shfl(o, 4 * g + 1);
            in2 = __shfl(o, 4 * g + 2);
            in3 = __shfl(o, 4 * g + 3);
        }

        const f32x4 s0v = aA0 + aB0 + aC0;
        const f32x4 s1v = aA1 + aB1 + aC1;

        // epilogue: tanh, hi/lo split via v_cvt_pk_bf16_f32, h' write, o-partials
        unsigned short* hw = hhi[p ^ 1];
        unsigned short* lw = hlo[p ^ 1];
        float op[4];
        #pragma unroll
        for (int r = 0; r < 4; ++r) {
            const float inr = (r == 0) ? in0 : (r == 1) ? in1 : (r == 2) ? in2 : in3;
            const float S0 = s0v[r] + bias0 + inr * wih0;
            const float S1 = s1v[r] + bias1 + inr * wih1;
            const float h0 = fast_tanh(S0);
            const float h1 = fast_tanh(S1);
            op[r] = h0 * wout0 + h1 * wout1;
            uint32_t P;
            asm("v_cvt_pk_bf16_f32 %0, %1, %2" : "=v"(P) : "v"(h0), "v"(h1));
            *(unsigned short*)((char*)hw + woffA[r]) = (unsigned short)P;
            *(unsigned short*)((char*)hw + woffB[r]) = (unsigned short)(P >> 16);
            const float hi0 = __builtin_bit_cast(float, P << 16);
            const float hi1 = __builtin_bit_cast(float, P & 0xffff0000u);
            const float lo0 = h0 - hi0;
            const float lo1 = h1 - hi1;
            uint32_t PL;
            asm("v_cvt_pk_bf16_f32 %0, %1, %2" : "=v"(PL) : "v"(lo0), "v"(lo1));
            *(unsigned short*)((char*)lw + woffA[r]) = (unsigned short)PL;
            *(unsigned short*)((char*)lw + woffB[r]) = (unsigned short)(PL >> 16);
        }
        // 2-stage shfl: each l15-quad's sum lands in all 4 of its lanes
        #pragma unroll
        for (int r = 0; r < 4; ++r) {
            op[r] += __shfl_xor(op[r], 1);
            op[r] += __shfl_xor(op[r], 2);
        }
        if ((l15 & 3) == 0) {
            #pragma unroll
            for (int r = 0; r < 4; ++r)
                opart[p][4 * g + r][4 * wid + (l15 >> 2)] = op[r];
        }
        __syncthreads();   // the one per-step barrier
    }

    // tail: finish o_{NSTEP-1}, then flush the last 64 outputs
    {
        const f32x4 opv = *(const f32x4*)&opart[(NSTEP - 1) & 1][l15][4 * g];
        float osum = opv[0] + opv[1] + opv[2] + opv[3];
        osum += __shfl_xor(osum, 16);
        osum += __shfl_xor(osum, 32);
        const float o = osum + bo;
        if (tid < 16) outbuf[((NSTEP - 1) >> 6) & 1][l15][(NSTEP - 1) & 63] = o;
    }
    __syncthreads();
    {
        const int base = TLEN;                 // 1024..1087
        const int q = (TLEN >> 6) & 1;         // buffer 0
        const int s = tid >> 4, c4 = (tid & 15) * 4;
        const f32x4 v = *(const f32x4*)&outbuf[q][s][c4];
        *(f32x4*)&out[(size_t)(s0 + s) * NSTEP + base + c4] = v;
    }
}

extern "C" void kernel_launch(void* const* d_in, const int* in_sizes, int n_in,
                              void* d_out, int out_size, void* d_ws, size_t ws_size,
                              hipStream_t stream) {
    const float* x     = (const float*)d_in[0];
    const float* W_ih  = (const float*)d_in[1];
    const float* W_hh  = (const float*)d_in[2];
    const float* b_ih  = (const float*)d_in[3];
    const float* b_hh  = (const float*)d_in[4];
    const float* W_out = (const float*)d_in[5];
    const float* b_out = (const float*)d_in[6];
    float* out = (float*)d_out;

    dim3 grid(2048 / SPB);   // 128 blocks x 16 samples
    dim3 block(NT);
    rnn_kernel<<<grid, block, 0, stream>>>(x, W_ih, W_hh, b_ih, b_hh,
                                           W_out, b_out, out);
}

// Round 5
// 1183.703 us; speedup vs baseline: 1.9748x; 1.0169x over previous
//
#include <hip/hip_runtime.h>
#include <stdint.h>
#include <math.h>

// RNN predictor: B=2048, T=1024 teacher-forced + FUT=64 autoregressive, H=128.
// Round-5: DS-pipe diet.
//  - h stored PACKED: one u32 per value = (bf16 hi | bf16 lo<<16). MFMA slot
//    map is shared by A and B, so W1=interleave(hi,lo) gives hihi+lolo and
//    W2=interleave(lo,hi) gives hilo+lohi -> all 4 split products, 8 b32
//    writes/thread (was 16 b16) and 8 b128 reads/wave of ONE buffer.
//  - o = W_out.h computed by 8 extra MFMAs against the already-loaded A-frags
//    (B nonzero only in col 0) -> replaces ~40 shuffle/opart DS ops. o_t
//    emerges at step t+1, exactly when the AR phase needs it as input.
//  - SPB=8, 256 blocks (full chip); A-reads exec-masked to l15<8 (rows 8-15
//    stay zero), h-writes masked to g<2 -> half DS bandwidth per instr.
//  - XOR swizzle dword ^= (row&7)<<2: reads uniform over banks, writes
//    conflict-free (audited).

#define TLEN  1024
#define FUT   64
#define HID   128
#define SPB   8
#define NT    256
#define NSTEP (TLEN + FUT)

typedef float f32x4 __attribute__((ext_vector_type(4)));
typedef short bf16x8 __attribute__((ext_vector_type(8)));

__device__ __forceinline__ float fast_tanh(float v) {
    return 1.0f - 2.0f / (__expf(2.0f * v) + 1.0f);   // saturates correctly
}
__device__ __forceinline__ unsigned short bf16_rn(float f) {
    uint32_t u = __builtin_bit_cast(uint32_t, f);
    uint32_t r = (u + 0x7fffu + ((u >> 16) & 1u)) >> 16;  // RNE
    return (unsigned short)r;
}
__device__ __forceinline__ float bf16f(unsigned short h) {
    uint32_t u = (uint32_t)h << 16;
    return __builtin_bit_cast(float, u);
}

__global__ __launch_bounds__(NT, 1) void rnn_kernel(
    const float* __restrict__ x,      // [B, T]
    const float* __restrict__ W_ih,   // [H, 1]
    const float* __restrict__ W_hh,   // [H, H]
    const float* __restrict__ b_ih,   // [H]
    const float* __restrict__ b_hh,   // [H]
    const float* __restrict__ W_out,  // [1, H]
    const float* __restrict__ b_out,  // [1]
    float* __restrict__ out)          // [B, T+FUT]
{
    __shared__ __align__(16) uint32_t hbuf[2][SPB * HID];   // packed (hi|lo), swizzled
    __shared__ __align__(16) float xstg[128][20];           // x chunk, padded
    __shared__ __align__(16) float outbuf[2][SPB][68];      // o ring, padded

    const int tid  = threadIdx.x;
    const int lane = tid & 63;
    const int wid  = tid >> 6;        // wave w: owns cols 32w..32w+31
    const int l15  = lane & 15;
    const int g    = lane >> 4;       // lane quarter
    const int s0   = blockIdx.x * SPB;

    // ---- persistent weight fragments ----
    // Slot map (shared by A and B): group G, slot s=8g+e -> bf16 element
    // 32G+s of the row; our packing puts (hi,lo) of real k=16G+4g+(e>>1)
    // at parities e&1. B lane n=l15 holds col j weights.
    const int j0 = wid * 32 + l15;
    const int j1 = j0 + 16;
    bf16x8 W1a[8], W2a[8], W1b[8], W2b[8], Wo[8];
    {
        const float* r0 = W_hh + (size_t)j0 * HID;
        const float* r1 = W_hh + (size_t)j1 * HID;
        #pragma unroll
        for (int G = 0; G < 8; ++G) {
            const int kb = G * 16 + g * 4;
            #pragma unroll
            for (int t = 0; t < 4; ++t) {
                const float wa = r0[kb + t];
                const float wb = r1[kb + t];
                const float wo = (l15 == 0) ? W_out[kb + t] : 0.0f;
                const unsigned short ha = bf16_rn(wa);
                const unsigned short la = bf16_rn(wa - bf16f(ha));
                const unsigned short hb_ = bf16_rn(wb);
                const unsigned short lb = bf16_rn(wb - bf16f(hb_));
                const unsigned short ho = bf16_rn(wo);
                const unsigned short lo_ = bf16_rn(wo - bf16f(ho));
                W1a[G][2 * t] = (short)ha;  W1a[G][2 * t + 1] = (short)la;
                W2a[G][2 * t] = (short)la;  W2a[G][2 * t + 1] = (short)ha;
                W1b[G][2 * t] = (short)hb_; W1b[G][2 * t + 1] = (short)lb;
                W2b[G][2 * t] = (short)lb;  W2b[G][2 * t + 1] = (short)hb_;
                Wo[G][2 * t]  = (short)ho;  Wo[G][2 * t + 1]  = (short)lo_;
            }
        }
    }
    const float bias0 = b_ih[j0] + b_hh[j0];
    const float bias1 = b_ih[j1] + b_hh[j1];
    const float wih0  = W_ih[j0], wih1 = W_ih[j1];
    const float bo    = b_out[0];

    // ---- LDS byte offsets; swizzle: byte ^= (row&7)<<4 (16B granule) ----
    // hbuf row = 512 B (128 u32). A-read: row l15, 16B at byte G*64+g*16.
    int aoff[8];
    #pragma unroll
    for (int G = 0; G < 8; ++G)
        aoff[G] = l15 * 512 + ((G * 64 + g * 16) ^ ((l15 & 7) << 4));
    // h-write: row 4g+r, one u32 at col j.
    int woffA[4], woffB[4];
    #pragma unroll
    for (int r = 0; r < 4; ++r) {
        const int row = 4 * g + r;
        const int swz = (row & 7) << 4;
        woffA[r] = row * 512 + ((4 * j0) ^ swz);
        woffB[r] = row * 512 + ((4 * j1) ^ swz);
    }

    for (int idx = tid; idx < SPB * HID; idx += NT) hbuf[0][idx] = 0;
    for (int idx = tid; idx < 128 * 20; idx += NT) ((float*)xstg)[idx] = 0.0f;
    __syncthreads();

    for (int i = 0; i < NSTEP; ++i) {
        const int p = i & 1;

        // refill x chunk every 128 teacher steps (coalesced along t)
        if (i < TLEN && (i & 127) == 0) {
            #pragma unroll
            for (int pass = 0; pass < 4; ++pass) {
                const int idx = pass * NT + tid;
                const int t = idx & 127, s = idx >> 7;
                xstg[t][s] = x[(size_t)(s0 + s) * TLEN + (i + t)];
            }
            __syncthreads();
        }

        // flush a full 64-entry output ring (o_{i-65}..o_{i-2})
        if (i > 64 && (i & 63) == 1 && tid < 128) {
            const int q = ((i - 65) >> 6) & 1;
            const int base = i - 65;
            const int s = tid >> 4, c4 = (tid & 15) * 4;
            const f32x4 v = *(const f32x4*)&outbuf[q][s][c4];
            *(f32x4*)&out[(size_t)(s0 + s) * NSTEP + base + c4] = v;
        }

        // A-fragments (rows 8-15 are zero; only l15<8 lanes read)
        const char* hbp = (const char*)hbuf[p];
        bf16x8 A[8];
        #pragma unroll
        for (int G = 0; G < 8; ++G) A[G] = (bf16x8){0,0,0,0,0,0,0,0};
        if (l15 < 8) {
            #pragma unroll
            for (int G = 0; G < 8; ++G)
                A[G] = *(const bf16x8*)(hbp + aoff[G]);
        }

        // 40 MFMA in 5 independent 8-deep chains
        f32x4 oa  = {0.f,0.f,0.f,0.f};
        f32x4 p10 = oa, p20 = oa, p11 = oa, p21 = oa;
        #pragma unroll
        for (int G = 0; G < 8; ++G) {
            oa  = __builtin_amdgcn_mfma_f32_16x16x32_bf16(A[G], Wo[G],  oa,  0, 0, 0);
            p10 = __builtin_amdgcn_mfma_f32_16x16x32_bf16(A[G], W1a[G], p10, 0, 0, 0);
            p11 = __builtin_amdgcn_mfma_f32_16x16x32_bf16(A[G], W1b[G], p11, 0, 0, 0);
            p20 = __builtin_amdgcn_mfma_f32_16x16x32_bf16(A[G], W2a[G], p20, 0, 0, 0);
            p21 = __builtin_amdgcn_mfma_f32_16x16x32_bf16(A[G], W2b[G], p21, 0, 0, 0);
        }

        // o_{i-1} (valid in lanes l15==0, g<2; rows m=4g+r)
        float oval[4];
        #pragma unroll
        for (int r = 0; r < 4; ++r) oval[r] = oa[r] + bo;

        if (i > 0 && (tid == 0 || tid == 16)) {
            const int q = ((i - 1) >> 6) & 1;
            const int c = (i - 1) & 63;
            #pragma unroll
            for (int r = 0; r < 4; ++r) outbuf[q][4 * g + r][c] = oval[r];
        }

        // per-row inputs (uniform branch)
        float in0, in1, in2, in3;
        if (i < TLEN) {
            const f32x4 xv = *(const f32x4*)&xstg[i & 127][4 * g];
            in0 = xv[0]; in1 = xv[1]; in2 = xv[2]; in3 = xv[3];
        } else {
            in0 = __shfl(oval[0], g << 4);
            in1 = __shfl(oval[1], g << 4);
            in2 = __shfl(oval[2], g << 4);
            in3 = __shfl(oval[3], g << 4);
        }

        // epilogue: S, tanh, pack (hi|lo) u32, masked writes
        char* hw = (char*)hbuf[p ^ 1];
        uint32_t pv0[4], pv1[4];
        #pragma unroll
        for (int r = 0; r < 4; ++r) {
            const float inr = (r == 0) ? in0 : (r == 1) ? in1 : (r == 2) ? in2 : in3;
            const float S0 = p10[r] + p20[r] + bias0 + inr * wih0;
            const float S1 = p11[r] + p21[r] + bias1 + inr * wih1;
            const float h0 = fast_tanh(S0);
            const float h1 = fast_tanh(S1);
            uint32_t P;
            asm("v_cvt_pk_bf16_f32 %0, %1, %2" : "=v"(P) : "v"(h0), "v"(h1));
            const float hi0 = __builtin_bit_cast(float, P << 16);
            const float hi1 = __builtin_bit_cast(float, P & 0xffff0000u);
            const float lo0 = h0 - hi0;
            const float lo1 = h1 - hi1;
            uint32_t PL;
            asm("v_cvt_pk_bf16_f32 %0, %1, %2" : "=v"(PL) : "v"(lo0), "v"(lo1));
            pv0[r] = (P & 0xffffu) | (PL << 16);          // (hi0, lo0)
            pv1[r] = (P >> 16) | (PL & 0xffff0000u);      // (hi1, lo1)
        }
        if (g < 2) {   // rows 0..7 only
            #pragma unroll
            for (int r = 0; r < 4; ++r) {
                *(uint32_t*)(hw + woffA[r]) = pv0[r];
                *(uint32_t*)(hw + woffB[r]) = pv1[r];
            }
        }
        __syncthreads();   // the one per-step barrier
    }

    // tail: o_{NSTEP-1} from the final h state (hbuf[0])
    {
        const char* hbp = (const char*)hbuf[NSTEP & 1];
        bf16x8 A[8];
        #pragma unroll
        for (int G = 0; G < 8; ++G) A[G] = (bf16x8){0,0,0,0,0,0,0,0};
        if (l15 < 8) {
            #pragma unroll
            for (int G = 0; G < 8; ++G)
                A[G] = *(const bf16x8*)(hbp + aoff[G]);
        }
        f32x4 oa = {0.f,0.f,0.f,0.f};
        #pragma unroll
        for (int G = 0; G < 8; ++G)
            oa = __builtin_amdgcn_mfma_f32_16x16x32_bf16(A[G], Wo[G], oa, 0, 0, 0);
        if (tid == 0 || tid == 16) {
            #pragma unroll
            for (int r = 0; r < 4; ++r)
                outbuf[((NSTEP - 1) >> 6) & 1][4 * g + r][63] = oa[r] + bo;
        }
    }
    __syncthreads();
    if (tid < 128) {   // flush t = 1024..1087
        const int s = tid >> 4, c4 = (tid & 15) * 4;
        const f32x4 v = *(const f32x4*)&outbuf[0][s][c4];
        *(f32x4*)&out[(size_t)(s0 + s) * NSTEP + TLEN + c4] = v;
    }
}

extern "C" void kernel_launch(void* const* d_in, const int* in_sizes, int n_in,
                              void* d_out, int out_size, void* d_ws, size_t ws_size,
                              hipStream_t stream) {
    const float* x     = (const float*)d_in[0];
    const float* W_ih  = (const float*)d_in[1];
    const float* W_hh  = (const float*)d_in[2];
    const float* b_ih  = (const float*)d_in[3];
    const float* b_hh  = (const float*)d_in[4];
    const float* W_out = (const float*)d_in[5];
    const float* b_out = (const float*)d_in[6];
    float* out = (float*)d_out;

    dim3 grid(2048 / SPB);   // 256 blocks -> 1 per CU, full chip
    dim3 block(NT);
    rnn_kernel<<<grid, block, 0, stream>>>(x, W_ih, W_hh, b_ih, b_hh,
                                           W_out, b_out, out);
}